// Round 15
// baseline (7732.829 us; speedup 1.0000x reference)
//
#include <hip/hip_runtime.h>
#include <cstddef>

#define BB 256   // batch
#define TT 4096  // time steps
#define HH 64    // hidden
#define NT 512   // 8 waves: waves 0-3 = group 0, waves 4-7 = group 1
#define CH 4     // chunk depth (steps)
#define NCH (TT / CH)
#define NPAIR 8  // 8 pairs x 32 batches
#define LOG2E 1.442695041f

typedef __attribute__((ext_vector_type(8))) short short8;   // 8 bf16 (4 VGPR)
typedef __attribute__((ext_vector_type(4))) short short4v;  // 4 bf16 (2 VGPR)
typedef __attribute__((ext_vector_type(4))) float floatx4;

// produced-chunk counters per (layer, pair): consumer (l,gb) polls row l-1.
__device__ int g_flags[3 * NPAIR];
__global__ void zero_flags_kernel() { g_flags[threadIdx.x] = 0; }

__device__ __forceinline__ floatx4 mfma16(short8 a, short8 b, floatx4 c) {
    return __builtin_amdgcn_mfma_f32_16x16x32_bf16(a, b, c, 0, 0, 0);
}
__device__ __forceinline__ float frcp(float x) { return __builtin_amdgcn_rcpf(x); }
__device__ __forceinline__ void lds_barrier() {
    asm volatile("s_waitcnt lgkmcnt(0)\n\ts_barrier" ::: "memory");
}
// fp32 -> bf16 hi/lo split (trunc; lo captures residual to ~2^-17 rel)
__device__ __forceinline__ void bf16split(float v, short& hi, short& lo) {
    unsigned u  = __float_as_uint(v);
    unsigned hu = u & 0xffff0000u;
    hi = (short)(hu >> 16);
    float r = v - __uint_as_float(hu);
    lo = (short)(__float_as_uint(r) >> 16);
}

// MFMA LSTM, R12 dataflow (fastest verified: 4469us) + R15: TWO independent
// batch-groups per block. Waves 0-3 run group 0, waves 4-7 run group 1 on the
// same SIMDs -> 2 waves/SIMD with independent dataflow = latency hiding that
// 1-wave/SIMD R12 lacked (R9's proven scalar lever, applied intra-block).
// CH=4 so both groups' LDS planes fit (92 KB). Same weights both groups.
// Grid = 32 blocks = 4 layers x 8 pairs; chunk flags per (layer,pair).
__global__ __attribute__((amdgpu_flat_work_group_size(NT, NT), amdgpu_waves_per_eu(2)))
void lstm_mfma(const float* __restrict__ xg,    // x [B][T][6]
               const float* __restrict__ Wih0,  // [256][6]
               const float* __restrict__ WihR,  // [3][256][64]
               const float* __restrict__ Whh4,  // [4][256][64]
               const float* __restrict__ bih4,  // [4][256]
               const float* __restrict__ bhh4,  // [4][256]
               float* __restrict__ seq)         // [T][B][64] in-place
{
    const int bid = blockIdx.x;
    const int l   = bid >> 3;
    const int gb  = bid & 7;
    const bool FIRST = (l == 0);
    const bool LAST  = (l == 3);
    const float* Wih = FIRST ? Wih0 : (WihR + (size_t)(l - 1) * 256 * HH);
    const float* Whh = Whh4 + (size_t)l * 256 * HH;
    int* const fin  = &g_flags[(l - 1) * NPAIR + gb];  // deref only if l>0
    int* const fout = &g_flags[l * NPAIR + gb];        // deref only if l<3

    const int tid  = threadIdx.x;
    const int grp  = tid >> 8;        // 0: waves 0-3, 1: waves 4-7
    const int tid2 = tid & 255;       // group-local thread id
    const int w    = (tid >> 6) & 3;  // group-local wave
    const int ln   = tid & 63;
    const int n    = ln & 15;         // batch col
    const int g4   = ln >> 4;         // 0..3
    const int k0   = (w << 4) + (g4 << 2);
    const int b0   = (gb << 5) + (grp << 4);   // this group's batch base

    // LDS planes (bf16), [grp] leading; row pad 72 -> conflict-tuned
    __shared__ __align__(16) unsigned short xhi[2][2][CH][16][72];
    __shared__ __align__(16) unsigned short xlo[2][2][CH][16][72];
    __shared__ __align__(16) unsigned short hhi[2][2][16][72];
    __shared__ __align__(16) unsigned short hlo[2][2][16][72];

    // ---- weight A-fragments (identical for both groups) ----
    short8 whi[4][4], wlo[4][4];
#pragma unroll
    for (int q = 0; q < 4; ++q) {
        const float sc = (q == 2) ? (-2.f * LOG2E) : (-LOG2E);
        const int gr = (q << 6) + (w << 4) + n;
#pragma unroll
        for (int s = 0; s < 4; ++s) {
            const int kb = s * 32 + g4 * 8;
            float wv[8];
#pragma unroll
            for (int i = 0; i < 8; ++i) {
                const int k = kb + i;
                float v;
                if (k < 64)      v = Whh[gr * 64 + k];
                else if (!FIRST) v = Wih[gr * 64 + (k - 64)];
                else             v = (k - 64 < 6) ? Wih[gr * 6 + (k - 64)] : 0.f;
                wv[i] = v * sc;
            }
            short8 hi, lo;
#pragma unroll
            for (int i = 0; i < 8; ++i) { short a, b2; bf16split(wv[i], a, b2); hi[i] = a; lo[i] = b2; }
            whi[q][s] = hi; wlo[q][s] = lo;
        }
    }
    floatx4 bias[4];
#pragma unroll
    for (int q = 0; q < 4; ++q) {
        const float sc = (q == 2) ? (-2.f * LOG2E) : (-LOG2E);
#pragma unroll
        for (int r = 0; r < 4; ++r) {
            const int gr = (q << 6) + k0 + r;
            bias[q][r] = (bih4[l * 256 + gr] + bhh4[l * 256 + gr]) * sc;
        }
    }

    // zero LDS (h(-1)=0; x pads / layer0 cols>=6 stay 0)
    {
        unsigned short* px = &xhi[0][0][0][0][0];
        unsigned short* py = &xlo[0][0][0][0][0];
        for (int i = tid; i < 2 * 2 * CH * 16 * 72; i += NT) { px[i] = 0; py[i] = 0; }
        unsigned short* ph_ = &hhi[0][0][0][0];
        unsigned short* pl_ = &hlo[0][0][0][0];
        for (int i = tid; i < 2 * 2 * 16 * 72; i += NT) { ph_[i] = 0; pl_[i] = 0; }
    }
    __syncthreads();

    // staging map (layers>=1): per group, 256 threads cover 4 rows x 16 b x 64H
    const int tt = tid2 >> 6;          // row 0..3
    const int sn = (tid2 >> 2) & 15;   // batch
    const int kh = (tid2 & 3) << 4;    // 16-float col base
    // layer0 map: tid2<64 -> (ttf = tid2>>4 row, nf = tid2&15 batch)
    const int ttf = tid2 >> 4;
    const int nf  = tid2 & 15;

    // ---- wait for producer chunk 0, stage into buf 0 ----
    if (!FIRST) {
        if (tid == 0)
            while (__hip_atomic_load(fin, __ATOMIC_ACQUIRE, __HIP_MEMORY_SCOPE_AGENT) < 1)
                __builtin_amdgcn_s_sleep(8);
        __syncthreads();
        const float* src = seq + ((size_t)tt * BB + b0 + sn) * HH + kh;
        floatx4 pv0[4];
#pragma unroll
        for (int m = 0; m < 4; ++m) pv0[m] = ((const floatx4*)src)[m];
#pragma unroll
        for (int m = 0; m < 2; ++m) {
            short8 hi8, lo8;
#pragma unroll
            for (int i = 0; i < 8; ++i) {
                const float v = (i < 4) ? pv0[2 * m][i] : pv0[2 * m + 1][i - 4];
                short a, b2; bf16split(v, a, b2); hi8[i] = a; lo8[i] = b2;
            }
            *(short8*)&xhi[grp][0][tt][sn][kh + 8 * m] = hi8;
            *(short8*)&xlo[grp][0][tt][sn][kh + 8 * m] = lo8;
        }
    } else if (tid2 < 64) {
        const float* sx = xg + ((size_t)(b0 + nf) * TT + ttf) * 6;
#pragma unroll
        for (int i = 0; i < 6; ++i) {
            short a, b2; bf16split(sx[i], a, b2);
            xhi[grp][0][ttf][nf][i] = (unsigned short)a;
            xlo[grp][0][ttf][nf][i] = (unsigned short)b2;
        }
    }
    float c0 = 0.f, c1 = 0.f, c2 = 0.f, c3 = 0.f;
    __syncthreads();

    for (int ck = 0; ck < NCH; ++ck) {
        const int buf = ck & 1;
        const bool pfv = (ck + 1 < NCH);
        if (!FIRST && pfv) {   // producer must have published chunk ck+1
            if (tid == 0)
                while (__hip_atomic_load(fin, __ATOMIC_ACQUIRE, __HIP_MEMORY_SCOPE_AGENT) < ck + 2)
                    __builtin_amdgcn_s_sleep(8);
            __syncthreads();
        }
        floatx4 pv[4];
        float xv[6];

#pragma unroll
        for (int ph = 0; ph < CH; ++ph) {
            const int t = ck * CH + ph;
            if (ph == 0 && pfv) {   // issue next-chunk staging loads
                if (!FIRST) {
                    const float* src = seq + ((size_t)((ck + 1) * CH + tt) * BB + b0 + sn) * HH + kh;
#pragma unroll
                    for (int m = 0; m < 4; ++m) pv[m] = ((const floatx4*)src)[m];
                } else if (tid2 < 64) {
                    const float* sx = xg + ((size_t)(b0 + nf) * TT + (ck + 1) * CH + ttf) * 6;
#pragma unroll
                    for (int i = 0; i < 6; ++i) xv[i] = sx[i];
                }
            }

            // B fragments (layout == fragment), group-local planes
            const short8 bx0 = *(const short8*)&xhi[grp][buf][ph][n][g4 * 8];
            const short8 bx1 = *(const short8*)&xhi[grp][buf][ph][n][32 + g4 * 8];
            const short8 by0 = *(const short8*)&xlo[grp][buf][ph][n][g4 * 8];
            const short8 by1 = *(const short8*)&xlo[grp][buf][ph][n][32 + g4 * 8];
            const int hb = (t + 1) & 1;
            const short8 bh0 = *(const short8*)&hhi[grp][hb][n][g4 * 8];
            const short8 bh1 = *(const short8*)&hhi[grp][hb][n][32 + g4 * 8];
            const short8 bl0 = *(const short8*)&hlo[grp][hb][n][g4 * 8];
            const short8 bl1 = *(const short8*)&hlo[grp][hb][n][32 + g4 * 8];

            // R12 dataflow verbatim: 4 chains, 12-deep, 3 terms
            floatx4 a0 = bias[0], a1 = bias[1], a2 = bias[2], a3 = bias[3];
#define TERM(bq0, bq1, bq2, bq3, W) \
            a0 = mfma16(W[0][0], bq0, a0); a1 = mfma16(W[1][0], bq0, a1); \
            a2 = mfma16(W[2][0], bq0, a2); a3 = mfma16(W[3][0], bq0, a3); \
            a0 = mfma16(W[0][1], bq1, a0); a1 = mfma16(W[1][1], bq1, a1); \
            a2 = mfma16(W[2][1], bq1, a2); a3 = mfma16(W[3][1], bq1, a3); \
            a0 = mfma16(W[0][2], bq2, a0); a1 = mfma16(W[1][2], bq2, a1); \
            a2 = mfma16(W[2][2], bq2, a2); a3 = mfma16(W[3][2], bq2, a3); \
            a0 = mfma16(W[0][3], bq3, a0); a1 = mfma16(W[1][3], bq3, a1); \
            a2 = mfma16(W[2][3], bq3, a2); a3 = mfma16(W[3][3], bq3, a3);
            TERM(bh0, bh1, bx0, bx1, whi)   // Whi . Shi
            TERM(bl0, bl1, by0, by1, whi)   // Whi . Slo
            TERM(bh0, bh1, bx0, bx1, wlo)   // Wlo . Shi
#undef TERM

            // lane-local epilogue
            floatx4 hv4;
            short4v h4hi, h4lo;
#define UNIT(r, cr) { \
            const float si = frcp(1.f + exp2f(a0[r])); \
            const float sf = frcp(1.f + exp2f(a1[r])); \
            const float tg = fmaf(2.f, frcp(1.f + exp2f(a2[r])), -1.f); \
            const float so = frcp(1.f + exp2f(a3[r])); \
            cr = fmaf(sf, cr, si * tg); \
            const float tc = fmaf(2.f, frcp(1.f + exp2f(cr * (-2.f * LOG2E))), -1.f); \
            const float hv = so * tc; \
            hv4[r] = hv; \
            short ha, hbs; bf16split(hv, ha, hbs); h4hi[r] = ha; h4lo[r] = hbs; }
            UNIT(0, c0) UNIT(1, c1) UNIT(2, c2) UNIT(3, c3)
#undef UNIT

            *(short4v*)&hhi[grp][t & 1][n][k0] = h4hi;
            *(short4v*)&hlo[grp][t & 1][n][k0] = h4lo;
            if (!LAST || t == TT - 1)
                *(floatx4*)(seq + ((size_t)t * BB + b0 + n) * HH + k0) = hv4;

            // land next-chunk staging: hi at ph1, lo at ph2 (layer0 at ph2)
            if (pfv) {
                if (!FIRST) {
                    if (ph == 1) {
#pragma unroll
                        for (int m = 0; m < 2; ++m) {
                            short8 hi8;
#pragma unroll
                            for (int i = 0; i < 8; ++i) {
                                const float v = (i < 4) ? pv[2 * m][i] : pv[2 * m + 1][i - 4];
                                short a, b2; bf16split(v, a, b2); hi8[i] = a;
                            }
                            *(short8*)&xhi[grp][1 - buf][tt][sn][kh + 8 * m] = hi8;
                        }
                    } else if (ph == 2) {
#pragma unroll
                        for (int m = 0; m < 2; ++m) {
                            short8 lo8;
#pragma unroll
                            for (int i = 0; i < 8; ++i) {
                                const float v = (i < 4) ? pv[2 * m][i] : pv[2 * m + 1][i - 4];
                                short a, b2; bf16split(v, a, b2); lo8[i] = b2;
                            }
                            *(short8*)&xlo[grp][1 - buf][tt][sn][kh + 8 * m] = lo8;
                        }
                    }
                } else if (ph == 2 && tid2 < 64) {
#pragma unroll
                    for (int i = 0; i < 6; ++i) {
                        short a, b2; bf16split(xv[i], a, b2);
                        xhi[grp][1 - buf][ttf][nf][i] = (unsigned short)a;
                        xlo[grp][1 - buf][ttf][nf][i] = (unsigned short)b2;
                    }
                }
            }

            if (ph < CH - 1) lds_barrier();   // LDS-only sync
            else             __syncthreads(); // chunk end: drains vm for publish
        }
        if (!LAST && tid == 0)
            __hip_atomic_store(fout, ck + 1, __ATOMIC_RELEASE, __HIP_MEMORY_SCOPE_AGENT);
    }
}

// out[b] = fc_b + sum_j relu(h[T-1][b][j]) * fc_w[j]
__global__ __launch_bounds__(256)
void fc_kernel(const float* __restrict__ seq, const float* __restrict__ fcw,
               const float* __restrict__ fcb, float* __restrict__ out)
{
    __shared__ float w[HH];
    const int tid = threadIdx.x;
    if (tid < HH) w[tid] = fcw[tid];
    __syncthreads();
    const float* h = &seq[((size_t)(TT - 1) * BB + tid) * HH];
    float s = fcb[0];
#pragma unroll
    for (int jj = 0; jj < HH; ++jj)
        s = fmaf(fmaxf(h[jj], 0.f), w[jj], s);
    out[tid] = s;
}

extern "C" void kernel_launch(void* const* d_in, const int* in_sizes, int n_in,
                              void* d_out, int out_size, void* d_ws, size_t ws_size,
                              hipStream_t stream) {
    const float* x    = (const float*)d_in[0];  // [B][T][6]
    const float* Wih0 = (const float*)d_in[1];  // [256][6]
    const float* WihR = (const float*)d_in[2];  // [3][256][64]
    const float* Whh  = (const float*)d_in[3];  // [4][256][64]
    const float* bih  = (const float*)d_in[4];  // [4][256]
    const float* bhh  = (const float*)d_in[5];  // [4][256]
    const float* fcw  = (const float*)d_in[6];  // [1][64]
    const float* fcb  = (const float*)d_in[7];  // [1]
    float* out = (float*)d_out;
    float* seq = (float*)d_ws;                  // [T][B][64] fp32 = 268 MB

    zero_flags_kernel<<<dim3(1), dim3(3 * NPAIR), 0, stream>>>();
    lstm_mfma<<<dim3(4 * NPAIR), dim3(NT), 0, stream>>>(x, Wih0, WihR, Whh, bih, bhh, seq);
    fc_kernel<<<dim3(1), dim3(256), 0, stream>>>(seq, fcw, fcb, out);
}